// Round 4
// baseline (1129.569 us; speedup 1.0000x reference)
//
#include <hip/hip_runtime.h>

#define NN 100000
#define EE 3200000
#define FIN 512
#define HH 16
#define CC 40

#define SHIFT 9
#define BNODES 512                       // nodes per bucket
#define NB ((NN + BNODES - 1) / BNODES)  // 196 buckets
#define CH 4096                          // edges per binning chunk
#define TC ((EE + CH - 1) / CH)          // 782 chunks
#define STR 17                           // LDS acc stride (pad 16 -> 17)

// ---------------- edge dtype detector ----------------
__global__ void k_detect(const int* __restrict__ ei, int* __restrict__ flag) {
    __shared__ int nz;
    int t = threadIdx.x;
    if (t == 0) nz = 0;
    __syncthreads();
    if (ei[2 * t + 1] != 0) atomicAdd(&nz, 1);
    __syncthreads();
    if (t == 0) flag[0] = (nz == 0) ? 1 : 0;  // 1 => int64 layout
}

// ---------------- coarse bucket histogram ----------------
__global__ void k_hist(const int* __restrict__ ei, const int* __restrict__ flag,
                       int* __restrict__ bcnt) {
    __shared__ int h[NB];
    for (int i = threadIdx.x; i < NB; i += 256) h[i] = 0;
    __syncthreads();
    int is64 = flag[0];
    for (int e = blockIdx.x * 256 + threadIdx.x; e < EE; e += gridDim.x * 256) {
        int dst = is64 ? ei[2 * (EE + e)] : ei[EE + e];
        atomicAdd(&h[dst >> SHIFT], 1);
    }
    __syncthreads();
    for (int i = threadIdx.x; i < NB; i += 256)
        if (h[i]) atomicAdd(&bcnt[i], h[i]);
}

// ---------------- scan bucket counts -> base & head ----------------
__global__ void k_bscan(const int* __restrict__ bcnt, int* __restrict__ base,
                        int* __restrict__ head) {
    __shared__ int ws[4];
    int t = threadIdx.x, lane = t & 63, wid = t >> 6;
    int v = (t < NB) ? bcnt[t] : 0;
    int orig = v;
#pragma unroll
    for (int off = 1; off < 64; off <<= 1) {
        int u = __shfl_up(v, off);
        if (lane >= off) v += u;
    }
    if (lane == 63) ws[wid] = v;
    __syncthreads();
    int add = 0;
    for (int w = 0; w < wid; ++w) add += ws[w];
    int incl = v + add;
    int excl = incl - orig;
    if (t < NB) { base[t] = excl; head[t] = excl; }
    if (t == NB - 1) base[NB] = incl;  // == EE
}

// ---------------- bin edges into bucket-segmented packed words ----------------
// word = (dst_local << 17) | src   (src < 2^17, dst_local < 512)
__global__ void k_bin(const int* __restrict__ ei, const int* __restrict__ flag,
                      int* __restrict__ head, unsigned* __restrict__ pairs) {
    __shared__ int h[NB];
    __shared__ int gbase[NB];
    __shared__ int lhead[NB];
    int t = threadIdx.x;
    int e0 = blockIdx.x * CH, e1 = min(EE, e0 + CH);
    int is64 = flag[0];
    for (int i = t; i < NB; i += 256) { h[i] = 0; lhead[i] = 0; }
    __syncthreads();
    for (int e = e0 + t; e < e1; e += 256) {
        int dst = is64 ? ei[2 * (EE + e)] : ei[EE + e];
        atomicAdd(&h[dst >> SHIFT], 1);
    }
    __syncthreads();
    for (int i = t; i < NB; i += 256)
        gbase[i] = h[i] ? atomicAdd(&head[i], h[i]) : 0;
    __syncthreads();
    for (int e = e0 + t; e < e1; e += 256) {
        int src = is64 ? ei[2 * e] : ei[e];
        int dst = is64 ? ei[2 * (EE + e)] : ei[EE + e];
        int b = dst >> SHIFT;
        int p = gbase[b] + atomicAdd(&lhead[b], 1);
        pairs[p] = ((unsigned)(dst & (BNODES - 1)) << 17) | (unsigned)src;
    }
}

// ---------------- per-bucket degree -> dinv ----------------
__global__ void k_deg(const unsigned* __restrict__ pairs, const int* __restrict__ base,
                      float* __restrict__ dinv) {
    __shared__ int h[BNODES];
    int b = blockIdx.x, t = threadIdx.x;
    for (int i = t; i < BNODES; i += 256) h[i] = 0;
    __syncthreads();
    int p0 = base[b], p1 = base[b + 1];
    for (int p = p0 + t; p < p1; p += 256) atomicAdd(&h[pairs[p] >> 17], 1);
    __syncthreads();
    for (int i = t; i < BNODES; i += 256) {
        int n = (b << SHIFT) + i;
        if (n < NN) dinv[n] = rsqrtf((float)(h[i] + 1));  // +1 self loop
    }
}

// ---------------- g1 = (x @ W1) * dinv : 4 threads/node, W1 in LDS ----------------
__global__ void __launch_bounds__(256) k_gemm1(const float* __restrict__ x,
                                               const float* __restrict__ W1,
                                               const float* __restrict__ dinv,
                                               float* __restrict__ g1) {
    __shared__ float w1s[FIN * HH];  // 32 KB
    int t = threadIdx.x;
    for (int i = t; i < FIN * HH; i += 256) w1s[i] = W1[i];
    __syncthreads();
    int gt = blockIdx.x * 256 + t;
    int node = gt >> 2, q = gt & 3;
    if (node >= NN) return;
    const float4* xr = reinterpret_cast<const float4*>(x + (size_t)node * FIN + q * 128);
    float acc[HH];
#pragma unroll
    for (int f = 0; f < HH; ++f) acc[f] = 0.f;
#pragma unroll 4
    for (int kq = 0; kq < 32; ++kq) {
        float4 xv = xr[kq];
        const float* wr = w1s + (q * 128 + kq * 4) * HH;
#pragma unroll
        for (int f = 0; f < HH; ++f) acc[f] = fmaf(xv.x, wr[f], acc[f]);
#pragma unroll
        for (int f = 0; f < HH; ++f) acc[f] = fmaf(xv.y, wr[HH + f], acc[f]);
#pragma unroll
        for (int f = 0; f < HH; ++f) acc[f] = fmaf(xv.z, wr[2 * HH + f], acc[f]);
#pragma unroll
        for (int f = 0; f < HH; ++f) acc[f] = fmaf(xv.w, wr[3 * HH + f], acc[f]);
    }
    // butterfly across the 4 K-quarter lanes
#pragma unroll
    for (int f = 0; f < HH; ++f) {
        acc[f] += __shfl_xor(acc[f], 1);
        acc[f] += __shfl_xor(acc[f], 2);
    }
    float di = dinv[node];
    float4 o = make_float4(acc[4 * q] * di, acc[4 * q + 1] * di,
                           acc[4 * q + 2] * di, acc[4 * q + 3] * di);
    reinterpret_cast<float4*>(g1)[node * 4 + q] = o;
}

// ---------------- aggA: edge-parallel LDS accumulate, relu epilogue -> g2h ------
__global__ void __launch_bounds__(1024) k_aggA(const float* __restrict__ g1,
                                               const unsigned* __restrict__ pairs,
                                               const int* __restrict__ base,
                                               const float* __restrict__ dinv,
                                               const float* __restrict__ b1,
                                               float* __restrict__ g2h) {
    __shared__ float acc[BNODES * STR];
    int b = blockIdx.x, t = threadIdx.x;
    for (int i = t; i < BNODES * STR; i += 1024) acc[i] = 0.f;
    __syncthreads();
    int p0 = base[b], p1 = base[b + 1];
    int q = t & 3;
    const float4* G = reinterpret_cast<const float4*>(g1);
    for (int e = p0 + (t >> 2); e < p1; e += 256) {
        unsigned w = pairs[e];
        int src = w & 0x1FFFF;
        int dl = w >> 17;
        float4 v = G[src * 4 + q];
        float* a = &acc[dl * STR + q * 4];
        atomicAdd(a + 0, v.x);
        atomicAdd(a + 1, v.y);
        atomicAdd(a + 2, v.z);
        atomicAdd(a + 3, v.w);
    }
    __syncthreads();
    int node = (b << SHIFT) + t;
    if (t < BNODES && node < NN) {
        float di = dinv[node];
        const float4* S = reinterpret_cast<const float4*>(g1 + (size_t)node * HH);
        float4* O = reinterpret_cast<float4*>(g2h + (size_t)node * HH);
        const float4* B = reinterpret_cast<const float4*>(b1);
#pragma unroll
        for (int k = 0; k < 4; ++k) {
            float4 sv = S[k];
            float4 bb = B[k];
            float* a = &acc[t * STR + 4 * k];
            float4 r;
            r.x = fmaxf(fmaf(di, a[0] + sv.x, bb.x), 0.f) * di;
            r.y = fmaxf(fmaf(di, a[1] + sv.y, bb.y), 0.f) * di;
            r.z = fmaxf(fmaf(di, a[2] + sv.z, bb.z), 0.f) * di;
            r.w = fmaxf(fmaf(di, a[3] + sv.w, bb.w), 0.f) * di;
            O[k] = r;
        }
    }
}

// ---------------- aggB: edge-parallel LDS accumulate, W2+log_softmax -> out -----
__global__ void __launch_bounds__(1024) k_aggB(const float* __restrict__ g2h,
                                               const unsigned* __restrict__ pairs,
                                               const int* __restrict__ base,
                                               const float* __restrict__ dinv,
                                               const float* __restrict__ W2,
                                               const float* __restrict__ b2,
                                               float* __restrict__ out) {
    __shared__ float acc[BNODES * STR];
    int b = blockIdx.x, t = threadIdx.x;
    for (int i = t; i < BNODES * STR; i += 1024) acc[i] = 0.f;
    __syncthreads();
    int p0 = base[b], p1 = base[b + 1];
    int q = t & 3;
    const float4* G = reinterpret_cast<const float4*>(g2h);
    for (int e = p0 + (t >> 2); e < p1; e += 256) {
        unsigned w = pairs[e];
        int src = w & 0x1FFFF;
        int dl = w >> 17;
        float4 v = G[src * 4 + q];
        float* a = &acc[dl * STR + q * 4];
        atomicAdd(a + 0, v.x);
        atomicAdd(a + 1, v.y);
        atomicAdd(a + 2, v.z);
        atomicAdd(a + 3, v.w);
    }
    __syncthreads();
    int node = (b << SHIFT) + t;
    if (t < BNODES && node < NN) {
        float di = dinv[node];
        float s[HH];
        const float4* S = reinterpret_cast<const float4*>(g2h + (size_t)node * HH);
#pragma unroll
        for (int k = 0; k < 4; ++k) {
            float4 sv = S[k];
            s[4 * k + 0] = acc[t * STR + 4 * k + 0] + sv.x;
            s[4 * k + 1] = acc[t * STR + 4 * k + 1] + sv.y;
            s[4 * k + 2] = acc[t * STR + 4 * k + 2] + sv.z;
            s[4 * k + 3] = acc[t * STR + 4 * k + 3] + sv.w;
        }
        float y[CC];
#pragma unroll
        for (int c = 0; c < CC; ++c) y[c] = 0.f;
#pragma unroll
        for (int f = 0; f < HH; ++f) {
            float sf = s[f];
            const float* w2r = W2 + f * CC;  // uniform -> scalar loads
#pragma unroll
            for (int c = 0; c < CC; ++c) y[c] = fmaf(sf, w2r[c], y[c]);
        }
        float m = -3.0e38f;
#pragma unroll
        for (int c = 0; c < CC; ++c) {
            y[c] = fmaf(di, y[c], b2[c]);
            m = fmaxf(m, y[c]);
        }
        float ssum = 0.f;
#pragma unroll
        for (int c = 0; c < CC; ++c) ssum += expf(y[c] - m);
        float l = logf(ssum) + m;
        float4* o = reinterpret_cast<float4*>(out + (size_t)node * CC);
#pragma unroll
        for (int k = 0; k < CC / 4; ++k)
            o[k] = make_float4(y[4 * k] - l, y[4 * k + 1] - l,
                               y[4 * k + 2] - l, y[4 * k + 3] - l);
    }
}

extern "C" void kernel_launch(void* const* d_in, const int* in_sizes, int n_in,
                              void* d_out, int out_size, void* d_ws, size_t ws_size,
                              hipStream_t stream) {
    const float* x  = (const float*)d_in[0];
    const int*   ei = (const int*)d_in[1];
    const float* W1 = (const float*)d_in[2];
    const float* b1 = (const float*)d_in[3];
    const float* W2 = (const float*)d_in[4];
    const float* b2 = (const float*)d_in[5];
    float* out = (float*)d_out;

    char* w = (char*)d_ws;
    auto alloc = [&](size_t bytes) {
        char* p = w;
        w += (bytes + 255) & ~(size_t)255;
        return p;
    };
    int*      flag  = (int*)alloc(256);
    int*      bcnt  = (int*)alloc((size_t)NB * 4);
    int*      base  = (int*)alloc((size_t)(NB + 1) * 4);
    int*      head  = (int*)alloc((size_t)NB * 4);
    float*    dinv  = (float*)alloc((size_t)NN * 4);
    unsigned* pairs = (unsigned*)alloc((size_t)EE * 4);
    float*    g1    = (float*)alloc((size_t)NN * HH * 4);
    float*    g2h   = (float*)alloc((size_t)NN * HH * 4);

    hipMemsetAsync(bcnt, 0, (size_t)NB * sizeof(int), stream);
    k_detect<<<1, 256, 0, stream>>>(ei, flag);
    k_hist<<<512, 256, 0, stream>>>(ei, flag, bcnt);
    k_bscan<<<1, 256, 0, stream>>>(bcnt, base, head);
    k_bin<<<TC, 256, 0, stream>>>(ei, flag, head, pairs);
    k_deg<<<NB, 256, 0, stream>>>(pairs, base, dinv);
    k_gemm1<<<(NN * 4 + 255) / 256, 256, 0, stream>>>(x, W1, dinv, g1);
    k_aggA<<<NB, 1024, 0, stream>>>(g1, pairs, base, dinv, b1, g2h);
    k_aggB<<<NB, 1024, 0, stream>>>(g2h, pairs, base, dinv, W2, b2, out);
}

// Round 5
// 525.273 us; speedup vs baseline: 2.1504x; 2.1504x over previous
//
#include <hip/hip_runtime.h>

#define NN 100000
#define EE 3200000
#define FIN 512
#define HH 16
#define CC 40

#define SHIFT 9
#define BNODES 512                       // nodes per bucket
#define NB 196                           // ceil(NN/BNODES)
#define CAP 20480                        // per-bucket slot capacity (mean 16384, +32 sigma)
#define CH 4096                          // edges per binning chunk
#define TC ((EE + CH - 1) / CH)          // 782 chunks

// bf16 helpers (manual RTNE; values here are finite and well-scaled)
__device__ __forceinline__ float bf2f(unsigned short u) {
    return __uint_as_float(((unsigned)u) << 16);
}
__device__ __forceinline__ unsigned short f2bf(float f) {
    unsigned b = __float_as_uint(f);
    return (unsigned short)((b + 0x7FFF + ((b >> 16) & 1)) >> 16);
}

// ---------------- edge dtype detector ----------------
__global__ void k_detect(const int* __restrict__ ei, int* __restrict__ flag) {
    __shared__ int nz;
    int t = threadIdx.x;
    if (t == 0) nz = 0;
    __syncthreads();
    if (ei[2 * t + 1] != 0) atomicAdd(&nz, 1);
    __syncthreads();
    if (t == 0) flag[0] = (nz == 0) ? 1 : 0;  // 1 => int64 layout
}

// ---------------- bin edges into fixed-capacity buckets (packed u32) ----------
// word = (dst_local << 17) | src   (src < 2^17, dst_local < 512)
__global__ void k_bin(const int* __restrict__ ei, const int* __restrict__ flag,
                      int* __restrict__ head, unsigned* __restrict__ pairs) {
    __shared__ int h[NB];
    __shared__ int gbase[NB];
    __shared__ int lhead[NB];
    int t = threadIdx.x;
    int e0 = blockIdx.x * CH, e1 = min(EE, e0 + CH);
    int is64 = flag[0];
    for (int i = t; i < NB; i += 256) { h[i] = 0; lhead[i] = 0; }
    __syncthreads();
    for (int e = e0 + t; e < e1; e += 256) {
        int dst = is64 ? ei[2 * (EE + e)] : ei[EE + e];
        atomicAdd(&h[dst >> SHIFT], 1);
    }
    __syncthreads();
    // one global reservation per (block,bucket): block-private contiguous runs
    for (int i = t; i < NB; i += 256)
        gbase[i] = h[i] ? atomicAdd(&head[i], h[i]) : 0;
    __syncthreads();
    for (int e = e0 + t; e < e1; e += 256) {
        int src = is64 ? ei[2 * e] : ei[e];
        int dst = is64 ? ei[2 * (EE + e)] : ei[EE + e];
        int b = dst >> SHIFT;
        int p = gbase[b] + atomicAdd(&lhead[b], 1);
        pairs[(size_t)b * CAP + p] = ((unsigned)(dst & (BNODES - 1)) << 17) | (unsigned)src;
    }
}

// ------- per-bucket: deg -> dinv, LDS scan -> ptr/pend, CSR scatter -> srcs ----
__global__ void k_build(const unsigned* __restrict__ pairs, const int* __restrict__ head,
                        int* __restrict__ ptr, int* __restrict__ pend,
                        float* __restrict__ dinv, int* __restrict__ srcs) {
    __shared__ int h[BNODES];
    __shared__ int lex[BNODES];
    __shared__ int ws[4];
    int b = blockIdx.x, t = threadIdx.x, lane = t & 63, wid = t >> 6;
    int node0 = b << SHIFT;
    int p0 = b * CAP;
    int cnt = head[b];
    for (int i = t; i < BNODES; i += 256) h[i] = 0;
    __syncthreads();
    for (int p = t; p < cnt; p += 256) atomicAdd(&h[pairs[p0 + p] >> 17], 1);
    __syncthreads();
    // exclusive scan over 512 counts: thread t owns elements 2t, 2t+1
    int a0 = h[2 * t], a1 = h[2 * t + 1];
    int s = a0 + a1;
    int v = s;
#pragma unroll
    for (int off = 1; off < 64; off <<= 1) {
        int u = __shfl_up(v, off);
        if (lane >= off) v += u;
    }
    if (lane == 63) ws[wid] = v;
    __syncthreads();
    int add = 0;
    for (int w = 0; w < wid; ++w) add += ws[w];
    int incl = v + add;
    int e0 = incl - s;
    lex[2 * t] = e0;
    lex[2 * t + 1] = e0 + a0;
    __syncthreads();
    for (int i = t; i < BNODES; i += 256) {
        int n = node0 + i;
        if (n < NN) {
            int st = p0 + lex[i];
            ptr[n] = st;
            pend[n] = st + h[i];
            dinv[n] = rsqrtf((float)(h[i] + 1));  // +1 self loop
        }
    }
    __syncthreads();
    for (int p = t; p < cnt; p += 256) {
        unsigned w = pairs[p0 + p];
        int pos = p0 + atomicAdd(&lex[w >> 17], 1);
        srcs[pos] = (int)(w & 0x1FFFF);
    }
}

// ---------------- g1 = bf16((x @ W1) * dinv) : 4 threads/node, W1 in LDS ------
__global__ void __launch_bounds__(256) k_gemm1(const float* __restrict__ x,
                                               const float* __restrict__ W1,
                                               const float* __restrict__ dinv,
                                               unsigned short* __restrict__ g1) {
    __shared__ float w1s[FIN * HH];  // 32 KB
    int t = threadIdx.x;
    for (int i = t; i < FIN * HH; i += 256) w1s[i] = W1[i];
    __syncthreads();
    int gt = blockIdx.x * 256 + t;
    int node = gt >> 2, q = gt & 3;
    if (node >= NN) return;
    const float4* xr = reinterpret_cast<const float4*>(x + (size_t)node * FIN + q * 128);
    float acc[HH];
#pragma unroll
    for (int f = 0; f < HH; ++f) acc[f] = 0.f;
#pragma unroll 4
    for (int kq = 0; kq < 32; ++kq) {
        float4 xv = xr[kq];
        const float* wr = w1s + (q * 128 + kq * 4) * HH;
#pragma unroll
        for (int f = 0; f < HH; ++f) acc[f] = fmaf(xv.x, wr[f], acc[f]);
#pragma unroll
        for (int f = 0; f < HH; ++f) acc[f] = fmaf(xv.y, wr[HH + f], acc[f]);
#pragma unroll
        for (int f = 0; f < HH; ++f) acc[f] = fmaf(xv.z, wr[2 * HH + f], acc[f]);
#pragma unroll
        for (int f = 0; f < HH; ++f) acc[f] = fmaf(xv.w, wr[3 * HH + f], acc[f]);
    }
    // butterfly across the 4 K-quarter lanes
#pragma unroll
    for (int f = 0; f < HH; ++f) {
        acc[f] += __shfl_xor(acc[f], 1);
        acc[f] += __shfl_xor(acc[f], 2);
    }
    float di = dinv[node];
    ushort4 o;
    o.x = f2bf(acc[4 * q + 0] * di);
    o.y = f2bf(acc[4 * q + 1] * di);
    o.z = f2bf(acc[4 * q + 2] * di);
    o.w = f2bf(acc[4 * q + 3] * di);
    reinterpret_cast<ushort4*>(g1)[node * 4 + q] = o;
}

// ---------------- agg1: CSR gather (bf16), relu epilogue -> g2h (bf16) --------
__global__ void k_agg1(const unsigned short* __restrict__ g1, const int* __restrict__ ptr,
                       const int* __restrict__ pend, const int* __restrict__ srcs,
                       const float* __restrict__ dinv, const float* __restrict__ b1,
                       unsigned short* __restrict__ g2h) {
    int gt = blockIdx.x * blockDim.x + threadIdx.x;
    int node = gt >> 2, q = gt & 3;
    if (node >= NN) return;
    const ushort4* G = reinterpret_cast<const ushort4*>(g1);
    ushort4 sv = G[node * 4 + q];  // self term
    float ax = bf2f(sv.x), ay = bf2f(sv.y), az = bf2f(sv.z), aw = bf2f(sv.w);
    float bx = 0.f, by = 0.f, bz = 0.f, bw = 0.f;
    float cx = 0.f, cy = 0.f, cz = 0.f, cw = 0.f;
    float dx = 0.f, dy = 0.f, dz = 0.f, dw = 0.f;
    int e = ptr[node], e1 = pend[node];
    for (; e + 3 < e1; e += 4) {
        int s0 = srcs[e], s1 = srcs[e + 1], s2 = srcs[e + 2], s3 = srcs[e + 3];
        ushort4 v0 = G[s0 * 4 + q];
        ushort4 v1 = G[s1 * 4 + q];
        ushort4 v2 = G[s2 * 4 + q];
        ushort4 v3 = G[s3 * 4 + q];
        ax += bf2f(v0.x); ay += bf2f(v0.y); az += bf2f(v0.z); aw += bf2f(v0.w);
        bx += bf2f(v1.x); by += bf2f(v1.y); bz += bf2f(v1.z); bw += bf2f(v1.w);
        cx += bf2f(v2.x); cy += bf2f(v2.y); cz += bf2f(v2.z); cw += bf2f(v2.w);
        dx += bf2f(v3.x); dy += bf2f(v3.y); dz += bf2f(v3.z); dw += bf2f(v3.w);
    }
    for (; e < e1; ++e) {
        ushort4 v = G[srcs[e] * 4 + q];
        ax += bf2f(v.x); ay += bf2f(v.y); az += bf2f(v.z); aw += bf2f(v.w);
    }
    ax += bx + cx + dx;
    ay += by + cy + dy;
    az += bz + cz + dz;
    aw += bw + cw + dw;
    float di = dinv[node];
    const float4 bb = reinterpret_cast<const float4*>(b1)[q];
    ushort4 r;
    r.x = f2bf(fmaxf(fmaf(di, ax, bb.x), 0.f) * di);
    r.y = f2bf(fmaxf(fmaf(di, ay, bb.y), 0.f) * di);
    r.z = f2bf(fmaxf(fmaf(di, az, bb.z), 0.f) * di);
    r.w = f2bf(fmaxf(fmaf(di, aw, bb.w), 0.f) * di);
    reinterpret_cast<ushort4*>(g2h)[node * 4 + q] = r;
}

// ---------------- agg2: CSR gather (bf16) -> sarr (f32) ----------------
__global__ void k_agg2(const unsigned short* __restrict__ g2h, const int* __restrict__ ptr,
                       const int* __restrict__ pend, const int* __restrict__ srcs,
                       float* __restrict__ sarr) {
    int gt = blockIdx.x * blockDim.x + threadIdx.x;
    int node = gt >> 2, q = gt & 3;
    if (node >= NN) return;
    const ushort4* G = reinterpret_cast<const ushort4*>(g2h);
    ushort4 sv = G[node * 4 + q];  // self term
    float ax = bf2f(sv.x), ay = bf2f(sv.y), az = bf2f(sv.z), aw = bf2f(sv.w);
    float bx = 0.f, by = 0.f, bz = 0.f, bw = 0.f;
    float cx = 0.f, cy = 0.f, cz = 0.f, cw = 0.f;
    float dx = 0.f, dy = 0.f, dz = 0.f, dw = 0.f;
    int e = ptr[node], e1 = pend[node];
    for (; e + 3 < e1; e += 4) {
        int s0 = srcs[e], s1 = srcs[e + 1], s2 = srcs[e + 2], s3 = srcs[e + 3];
        ushort4 v0 = G[s0 * 4 + q];
        ushort4 v1 = G[s1 * 4 + q];
        ushort4 v2 = G[s2 * 4 + q];
        ushort4 v3 = G[s3 * 4 + q];
        ax += bf2f(v0.x); ay += bf2f(v0.y); az += bf2f(v0.z); aw += bf2f(v0.w);
        bx += bf2f(v1.x); by += bf2f(v1.y); bz += bf2f(v1.z); bw += bf2f(v1.w);
        cx += bf2f(v2.x); cy += bf2f(v2.y); cz += bf2f(v2.z); cw += bf2f(v2.w);
        dx += bf2f(v3.x); dy += bf2f(v3.y); dz += bf2f(v3.z); dw += bf2f(v3.w);
    }
    for (; e < e1; ++e) {
        ushort4 v = G[srcs[e] * 4 + q];
        ax += bf2f(v.x); ay += bf2f(v.y); az += bf2f(v.z); aw += bf2f(v.w);
    }
    ax += bx + cx + dx;
    ay += by + cy + dy;
    az += bz + cz + dz;
    aw += bw + cw + dw;
    reinterpret_cast<float4*>(sarr)[node * 4 + q] = make_float4(ax, ay, az, aw);
}

// ---------------- node-local: y = di*(s@W2)+b2 ; out = log_softmax(y) ---------
__global__ void k_out(const float* __restrict__ sarr, const float* __restrict__ dinv,
                      const float* __restrict__ W2, const float* __restrict__ b2,
                      float* __restrict__ out) {
    int i = blockIdx.x * blockDim.x + threadIdx.x;
    if (i >= NN) return;
    float s[HH];
    {
        const float4* sp = reinterpret_cast<const float4*>(sarr + (size_t)i * HH);
#pragma unroll
        for (int qk = 0; qk < HH / 4; ++qk) {
            float4 v = sp[qk];
            s[4 * qk] = v.x; s[4 * qk + 1] = v.y; s[4 * qk + 2] = v.z; s[4 * qk + 3] = v.w;
        }
    }
    float di = dinv[i];
    float y[CC];
#pragma unroll
    for (int c = 0; c < CC; ++c) y[c] = 0.f;
#pragma unroll
    for (int f = 0; f < HH; ++f) {
        float sf = s[f];
        const float* w2r = W2 + f * CC;  // uniform -> scalar loads
#pragma unroll
        for (int c = 0; c < CC; ++c) y[c] = fmaf(sf, w2r[c], y[c]);
    }
    float m = -3.0e38f;
#pragma unroll
    for (int c = 0; c < CC; ++c) {
        y[c] = fmaf(di, y[c], b2[c]);
        m = fmaxf(m, y[c]);
    }
    float ssum = 0.f;
#pragma unroll
    for (int c = 0; c < CC; ++c) ssum += expf(y[c] - m);
    float l = logf(ssum) + m;
    float4* o = reinterpret_cast<float4*>(out + (size_t)i * CC);
#pragma unroll
    for (int qk = 0; qk < CC / 4; ++qk)
        o[qk] = make_float4(y[4 * qk] - l, y[4 * qk + 1] - l,
                            y[4 * qk + 2] - l, y[4 * qk + 3] - l);
}

extern "C" void kernel_launch(void* const* d_in, const int* in_sizes, int n_in,
                              void* d_out, int out_size, void* d_ws, size_t ws_size,
                              hipStream_t stream) {
    const float* x  = (const float*)d_in[0];
    const int*   ei = (const int*)d_in[1];
    const float* W1 = (const float*)d_in[2];
    const float* b1 = (const float*)d_in[3];
    const float* W2 = (const float*)d_in[4];
    const float* b2 = (const float*)d_in[5];
    float* out = (float*)d_out;

    char* w = (char*)d_ws;
    auto alloc = [&](size_t bytes) {
        char* p = w;
        w += (bytes + 255) & ~(size_t)255;
        return p;
    };
    int*            flag  = (int*)alloc(256);
    int*            head  = (int*)alloc((size_t)NB * 4);
    int*            ptr   = (int*)alloc((size_t)NN * 4);
    int*            pend  = (int*)alloc((size_t)NN * 4);
    float*          dinv  = (float*)alloc((size_t)NN * 4);
    unsigned*       pairs = (unsigned*)alloc((size_t)NB * CAP * 4);  // 16 MB
    int*            srcs  = (int*)alloc((size_t)NB * CAP * 4);       // 16 MB
    unsigned short* g1    = (unsigned short*)alloc((size_t)NN * HH * 2);
    unsigned short* g2h   = (unsigned short*)alloc((size_t)NN * HH * 2);
    float*          sarr  = (float*)alloc((size_t)NN * HH * 4);

    hipMemsetAsync(head, 0, (size_t)NB * sizeof(int), stream);
    k_detect<<<1, 256, 0, stream>>>(ei, flag);
    k_bin<<<TC, 256, 0, stream>>>(ei, flag, head, pairs);
    k_build<<<NB, 256, 0, stream>>>(pairs, head, ptr, pend, dinv, srcs);
    int nt = NN * 4;
    k_gemm1<<<(nt + 255) / 256, 256, 0, stream>>>(x, W1, dinv, g1);
    k_agg1<<<(nt + 255) / 256, 256, 0, stream>>>(g1, ptr, pend, srcs, dinv, b1, g2h);
    k_agg2<<<(nt + 255) / 256, 256, 0, stream>>>(g2h, ptr, pend, srcs, sarr);
    k_out<<<(NN + 255) / 256, 256, 0, stream>>>(sarr, dinv, W2, b2, out);
}